// Round 1
// baseline (1207.938 us; speedup 1.0000x reference)
//
#include <hip/hip_runtime.h>
#include <hip/hip_bf16.h>
#include <math.h>

// Problem constants (from reference setup_inputs)
#define BB 8
#define SS 8192
#define DD 512
#define HH 256
#define MM (BB * SS)        // 65536 rows
// Scan chunking
#define CC 64               // chunks
#define LL 128              // chunk length (CC*LL == SS)

// GEMM tiling
#define TILE_M 64
#define TILE_H 16           // h columns per block -> 48 W rows (3 gates)
#define TILE_K 32

__device__ __forceinline__ float softplusf(float z) {
    // log(1+exp(z)); stable for large |z|
    if (z > 20.0f) return z;
    return log1pf(expf(z));
}

__device__ __forceinline__ float sigmoidf_(float z) {
    return 1.0f / (1.0f + expf(-z));
}

// Fused GEMM + gate kernel.
// Computes y[m, h'], h' in {h, H+h, 2H+h} for h in [h0, h0+16),
// then F = exp(log_f), u = exp(log_i + log_g(h_raw)), stores F to F_arr, u to u_out.
__global__ __launch_bounds__(256) void gemm_gate(
    const float* __restrict__ x,      // [M, D]
    const float* __restrict__ W,      // [3H, D]
    float* __restrict__ F_arr,        // [M, H]
    float* __restrict__ u_out)        // [M, H]  (this is d_out, overwritten later)
{
    const int m0 = blockIdx.x * TILE_M;
    const int h0 = blockIdx.y * TILE_H;

    __shared__ float As[TILE_K][68];  // transposed A tile, padded to 68 (16B-aligned rows)
    __shared__ float Bs[TILE_K][52];  // transposed B tile (48 W rows), padded

    const int tid = threadIdx.x;
    const int tc = tid & 15;          // h column within tile
    const int tr = tid >> 4;          // row group (handles rows tr*4 .. tr*4+3)

    float accf[4] = {0.f, 0.f, 0.f, 0.f};
    float acci[4] = {0.f, 0.f, 0.f, 0.f};
    float acch[4] = {0.f, 0.f, 0.f, 0.f};

    for (int k0 = 0; k0 < DD; k0 += TILE_K) {
        // Stage A tile: 64 rows x 32 cols = 512 float4 loads, 2 per thread
        #pragma unroll
        for (int i = 0; i < 2; ++i) {
            int idx = tid + i * 256;         // 0..511
            int row = idx >> 3;              // 0..63
            int l8  = idx & 7;               // 0..7
            const float4 v = *(const float4*)(x + (size_t)(m0 + row) * DD + k0 + l8 * 4);
            As[l8 * 4 + 0][row] = v.x;
            As[l8 * 4 + 1][row] = v.y;
            As[l8 * 4 + 2][row] = v.z;
            As[l8 * 4 + 3][row] = v.w;
        }
        // Stage B tile: 48 W rows x 32 cols = 384 float4 loads
        #pragma unroll
        for (int i = 0; i < 2; ++i) {
            int idx = tid + i * 256;
            if (idx < 384) {
                int r48 = idx >> 3;          // 0..47
                int l8  = idx & 7;
                int g   = r48 >> 4;          // gate 0,1,2
                int hh  = r48 & 15;
                const float4 v = *(const float4*)(W + (size_t)(g * HH + h0 + hh) * DD + k0 + l8 * 4);
                Bs[l8 * 4 + 0][r48] = v.x;
                Bs[l8 * 4 + 1][r48] = v.y;
                Bs[l8 * 4 + 2][r48] = v.z;
                Bs[l8 * 4 + 3][r48] = v.w;
            }
        }
        __syncthreads();

        #pragma unroll
        for (int kk = 0; kk < TILE_K; ++kk) {
            const float4 a = *(const float4*)&As[kk][tr * 4];
            const float b0 = Bs[kk][tc];
            const float b1 = Bs[kk][16 + tc];
            const float b2 = Bs[kk][32 + tc];
            accf[0] += a.x * b0; accf[1] += a.y * b0; accf[2] += a.z * b0; accf[3] += a.w * b0;
            acci[0] += a.x * b1; acci[1] += a.y * b1; acci[2] += a.z * b1; acci[3] += a.w * b1;
            acch[0] += a.x * b2; acch[1] += a.y * b2; acch[2] += a.z * b2; acch[3] += a.w * b2;
        }
        __syncthreads();
    }

    // Epilogue: gate math, store F and u
    #pragma unroll
    for (int j = 0; j < 4; ++j) {
        const int m = m0 + tr * 4 + j;
        const int h = h0 + tc;
        const float fr = accf[j];
        const float ir = acci[j];
        const float hr = acch[j];
        // diff = softplus(-f) - softplus(-i)
        const float diff = softplusf(-fr) - softplusf(-ir);
        // F = exp(-softplus(diff)) = sigmoid(-diff); I = sigmoid(diff)
        const float F = 1.0f / (1.0f + expf(diff));
        const float I = 1.0f / (1.0f + expf(-diff));
        // g(h_raw)
        const float G = (hr >= 0.0f) ? (hr + 0.5f) : sigmoidf_(hr);
        const float u = I * G;
        const size_t o = (size_t)m * HH + h;
        F_arr[o] = F;
        u_out[o] = u;
    }
}

// Pass 1: per (b, chunk, h): P = prod F over chunk, U = local scan with zero init.
__global__ __launch_bounds__(256) void scan_pass1(
    const float* __restrict__ F_arr,
    const float* __restrict__ u_arr,
    float* __restrict__ P_arr,        // [C, B, H]
    float* __restrict__ U_arr)        // [C, B, H]
{
    const int bc = blockIdx.x;        // b*CC + c
    const int b = bc / CC;
    const int c = bc % CC;
    const int h = threadIdx.x;
    size_t base = ((size_t)(b * SS + c * LL)) * HH + h;
    float P = 1.0f, U = 0.0f;
    #pragma unroll 4
    for (int t = 0; t < LL; ++t) {
        const float F = F_arr[base];
        const float u = u_arr[base];
        U = F * U + u;
        P = P * F;
        base += HH;
    }
    const size_t o = ((size_t)c * BB + b) * HH + h;
    P_arr[o] = P;
    U_arr[o] = U;
}

// Pass 2: sequential combine over chunks per (b,h); writes chunk-entry h value.
__global__ __launch_bounds__(256) void scan_pass2(
    const float* __restrict__ h_prev, // [B, H]
    const float* __restrict__ P_arr,
    const float* __restrict__ U_arr,
    float* __restrict__ Hin)          // [C, B, H]
{
    const int b = blockIdx.x;
    const int h = threadIdx.x;
    const float z = h_prev[b * HH + h];
    float carry = (z >= 0.0f) ? (z + 0.5f) : sigmoidf_(z);  // g(h_prev)
    for (int c = 0; c < CC; ++c) {
        const size_t o = ((size_t)c * BB + b) * HH + h;
        Hin[o] = carry;
        carry = P_arr[o] * carry + U_arr[o];
    }
}

// Pass 3: re-scan each chunk with correct entry value; overwrite u (=d_out) with h_t.
__global__ __launch_bounds__(256) void scan_pass3(
    const float* __restrict__ F_arr,
    const float* __restrict__ Hin,
    float* __restrict__ out)          // holds u on entry, h_t on exit
{
    const int bc = blockIdx.x;
    const int b = bc / CC;
    const int c = bc % CC;
    const int h = threadIdx.x;
    float hv = Hin[((size_t)c * BB + b) * HH + h];
    size_t base = ((size_t)(b * SS + c * LL)) * HH + h;
    #pragma unroll 4
    for (int t = 0; t < LL; ++t) {
        const float F = F_arr[base];
        const float u = out[base];
        hv = F * hv + u;
        out[base] = hv;
        base += HH;
    }
}

extern "C" void kernel_launch(void* const* d_in, const int* in_sizes, int n_in,
                              void* d_out, int out_size, void* d_ws, size_t ws_size,
                              hipStream_t stream) {
    const float* x      = (const float*)d_in[0];   // [B,S,D]
    const float* h_prev = (const float*)d_in[1];   // [B,H]
    const float* W      = (const float*)d_in[2];   // [3H,D]
    float* out = (float*)d_out;                    // [B,S,H]

    // Workspace layout (floats): F_arr[M*H] | P[C*B*H] | U[C*B*H] | Hin[C*B*H]
    float* F_arr = (float*)d_ws;
    float* P_arr = F_arr + (size_t)MM * HH;
    float* U_arr = P_arr + (size_t)CC * BB * HH;
    float* Hin   = U_arr + (size_t)CC * BB * HH;

    dim3 g1(MM / TILE_M, HH / TILE_H);   // (1024, 16)
    gemm_gate<<<g1, 256, 0, stream>>>(x, W, F_arr, out);
    scan_pass1<<<BB * CC, HH, 0, stream>>>(F_arr, out, P_arr, U_arr);
    scan_pass2<<<BB, HH, 0, stream>>>(h_prev, P_arr, U_arr, Hin);
    scan_pass3<<<BB * CC, HH, 0, stream>>>(F_arr, Hin, out);
}

// Round 2
// 387.865 us; speedup vs baseline: 3.1143x; 3.1143x over previous
//
#include <hip/hip_runtime.h>
#include <math.h>

// Problem constants
#define BB 8
#define SS 8192
#define DD 512
#define HH 256
#define MM (BB * SS)        // 65536 rows
#define NN (3 * HH)         // 768 GEMM columns
// Scan chunking
#define CC 64
#define LL 128

typedef unsigned short u16;
typedef __attribute__((ext_vector_type(8))) short short8;   // 8 bf16 (4 VGPRs) - MFMA A/B frag
typedef __attribute__((ext_vector_type(4))) float f32x4;    // MFMA C/D frag

#define AS1(p) ((const __attribute__((address_space(1))) void*)(p))
#define AS3(p) ((__attribute__((address_space(3))) void*)(p))

__device__ __forceinline__ u16 f2bf(float f) {
    union { float f; unsigned u; } v; v.f = f;
    unsigned r = v.u + 0x7fffu + ((v.u >> 16) & 1u);   // RTNE (inputs are finite)
    return (u16)(r >> 16);
}

__device__ __forceinline__ float sp_fast(float z) {    // softplus
    return (z > 15.0f) ? z : __logf(1.0f + __expf(z));
}

// ---- x fp32 [M,D] -> bf16, stored into d_out (same byte size: M*D*2 == M*H*4) ----
__global__ __launch_bounds__(256) void convert_x(const float4* __restrict__ x,
                                                 ushort4* __restrict__ xb, int n4) {
    int i = blockIdx.x * blockDim.x + threadIdx.x;
    const int stride = gridDim.x * blockDim.x;
    for (; i < n4; i += stride) {
        const float4 v = x[i];
        ushort4 o;
        o.x = f2bf(v.x); o.y = f2bf(v.y); o.z = f2bf(v.z); o.w = f2bf(v.w);
        xb[i] = o;
    }
}

// ---- W fp32 [3H,D] -> Wr bf16 [768,512], rows reordered so that
//      orow = hg*48 + g*16 + hl  <-  irow = g*256 + hg*16 + hl   (head = hg*16+hl)
__global__ __launch_bounds__(128) void convert_W(const float* __restrict__ W,
                                                 u16* __restrict__ Wr) {
    const int orow = blockIdx.x;            // 0..767
    const int hg = orow / 48, rem = orow % 48;
    const int g = rem >> 4, hl = rem & 15;
    const int irow = g * HH + hg * 16 + hl;
    const int t = threadIdx.x;              // 128 threads x 4 elems
    const float4 v = *(const float4*)&W[(size_t)irow * DD + t * 4];
    ushort4 o;
    o.x = f2bf(v.x); o.y = f2bf(v.y); o.z = f2bf(v.z); o.w = f2bf(v.w);
    *(ushort4*)&Wr[(size_t)orow * DD + t * 4] = o;
}

// ---- Fused MFMA GEMM + gates. Block: 512 threads (8 waves), BM=64, BN=768 (full), BK=32.
//      xbuf = d_out: holds bf16 x on entry; epilogue overwrites this block's own rows
//      with fp32 u (all reads of those rows complete before the last barrier).
__global__ __launch_bounds__(512) void gemm_gate_mfma(
    const u16* __restrict__ Wr,       // [768,512] bf16 reordered
    float* __restrict__ F_arr,        // [M,H] fp32
    void* xbuf)                       // d_out: in = bf16 x [M,512], out = fp32 u [M,256]
{
    __shared__ __align__(16) u16 As[64 * 32];     // 4 KB
    __shared__ __align__(16) u16 Bs[NN * 32];     // 48 KB

    const u16* xb = (const u16*)xbuf;
    float* u_out = (float*)xbuf;

    const int tid = threadIdx.x;
    const int m0 = blockIdx.x * 64;
    const int w = tid >> 6;          // wave 0..7 -> head-group pair 2w,2w+1
    const int lane = tid & 63;
    const int l16 = lane & 15;
    const int quad = lane >> 4;      // 0..3

    f32x4 acc[4][6];
    #pragma unroll
    for (int a = 0; a < 4; ++a)
        #pragma unroll
        for (int b = 0; b < 6; ++b)
            #pragma unroll
            for (int e = 0; e < 4; ++e) acc[a][b][e] = 0.0f;

    for (int kit = 0; kit < DD / 32; ++kit) {
        const int k0 = kit * 32;
        __syncthreads();
        // Stage B tile: 768x32 bf16 = 3072 16B-loads, 6 per thread
        #pragma unroll
        for (int i = 0; i < 6; ++i) {
            const int idx = tid + 512 * i;               // 0..3071
            const u16* g = Wr + ((size_t)(idx >> 2) * DD + k0 + (idx & 3) * 8);
            __builtin_amdgcn_global_load_lds(AS1(g), AS3(Bs + (size_t)idx * 8), 16, 0, 0);
        }
        // Stage A tile: 64x32 bf16 = 256 16B-loads (waves 0..3)
        if (tid < 256) {
            const int idx = tid;
            const u16* g = xb + ((size_t)(m0 + (idx >> 2)) * DD + k0 + (idx & 3) * 8);
            __builtin_amdgcn_global_load_lds(AS1(g), AS3(As + (size_t)idx * 8), 16, 0, 0);
        }
        __syncthreads();

        short8 a[4], b[6];
        #pragma unroll
        for (int mf = 0; mf < 4; ++mf)
            a[mf] = *(const short8*)&As[(mf * 16 + l16) * 32 + quad * 8];
        #pragma unroll
        for (int nf = 0; nf < 6; ++nf)
            b[nf] = *(const short8*)&Bs[(w * 96 + nf * 16 + l16) * 32 + quad * 8];
        #pragma unroll
        for (int mf = 0; mf < 4; ++mf)
            #pragma unroll
            for (int nf = 0; nf < 6; ++nf)
                acc[mf][nf] = __builtin_amdgcn_mfma_f32_16x16x32_bf16(
                    a[mf], b[nf], acc[mf][nf], 0, 0, 0);
    }

    // Epilogue: gates. acc[mf][hgl*3+g] -> f,i,h co-located per lane.
    #pragma unroll
    for (int mf = 0; mf < 4; ++mf) {
        #pragma unroll
        for (int hgl = 0; hgl < 2; ++hgl) {
            const int head = (2 * w + hgl) * 16 + l16;
            #pragma unroll
            for (int r = 0; r < 4; ++r) {
                const int m = m0 + mf * 16 + quad * 4 + r;
                const float fr = acc[mf][hgl * 3 + 0][r];
                const float ir = acc[mf][hgl * 3 + 1][r];
                const float hr = acc[mf][hgl * 3 + 2][r];
                const float diff = sp_fast(-fr) - sp_fast(-ir);
                const float F = __builtin_amdgcn_rcpf(1.0f + __expf(diff));  // sigmoid(-diff)
                const float I = 1.0f - F;                                     // sigmoid(diff)
                const float G = (hr >= 0.0f) ? (hr + 0.5f)
                                             : __builtin_amdgcn_rcpf(1.0f + __expf(-hr));
                const size_t o = (size_t)m * HH + head;
                F_arr[o] = F;
                u_out[o] = I * G;
            }
        }
    }
}

// ---- Scan passes (proven in round 1) ----
__global__ __launch_bounds__(256) void scan_pass1(
    const float* __restrict__ F_arr, const float* __restrict__ u_arr,
    float* __restrict__ P_arr, float* __restrict__ U_arr) {
    const int bc = blockIdx.x;
    const int b = bc / CC;
    const int c = bc % CC;
    const int h = threadIdx.x;
    size_t base = ((size_t)(b * SS + c * LL)) * HH + h;
    float P = 1.0f, U = 0.0f;
    #pragma unroll 4
    for (int t = 0; t < LL; ++t) {
        const float F = F_arr[base];
        const float u = u_arr[base];
        U = F * U + u;
        P = P * F;
        base += HH;
    }
    const size_t o = ((size_t)c * BB + b) * HH + h;
    P_arr[o] = P;
    U_arr[o] = U;
}

__global__ __launch_bounds__(256) void scan_pass2(
    const float* __restrict__ h_prev, const float* __restrict__ P_arr,
    const float* __restrict__ U_arr, float* __restrict__ Hin) {
    const int b = blockIdx.x;
    const int h = threadIdx.x;
    const float z = h_prev[b * HH + h];
    float carry = (z >= 0.0f) ? (z + 0.5f) : __builtin_amdgcn_rcpf(1.0f + __expf(-z));
    for (int c = 0; c < CC; ++c) {
        const size_t o = ((size_t)c * BB + b) * HH + h;
        Hin[o] = carry;
        carry = P_arr[o] * carry + U_arr[o];
    }
}

__global__ __launch_bounds__(256) void scan_pass3(
    const float* __restrict__ F_arr, const float* __restrict__ Hin,
    float* __restrict__ out) {
    const int bc = blockIdx.x;
    const int b = bc / CC;
    const int c = bc % CC;
    const int h = threadIdx.x;
    float hv = Hin[((size_t)c * BB + b) * HH + h];
    size_t base = ((size_t)(b * SS + c * LL)) * HH + h;
    #pragma unroll 4
    for (int t = 0; t < LL; ++t) {
        const float F = F_arr[base];
        const float u = out[base];
        hv = F * hv + u;
        out[base] = hv;
        base += HH;
    }
}

extern "C" void kernel_launch(void* const* d_in, const int* in_sizes, int n_in,
                              void* d_out, int out_size, void* d_ws, size_t ws_size,
                              hipStream_t stream) {
    const float* x      = (const float*)d_in[0];   // [B,S,D]
    const float* h_prev = (const float*)d_in[1];   // [B,H]
    const float* W      = (const float*)d_in[2];   // [3H,D]

    // Workspace layout: F_arr [M*H] f32 | P | U | Hin | Wr [768*512] bf16
    float* F_arr = (float*)d_ws;
    float* P_arr = F_arr + (size_t)MM * HH;
    float* U_arr = P_arr + (size_t)CC * BB * HH;
    float* Hin   = U_arr + (size_t)CC * BB * HH;
    u16*   Wr    = (u16*)(Hin + (size_t)CC * BB * HH);

    // 1) x -> bf16 into d_out (exact same byte size)
    convert_x<<<4096, 256, 0, stream>>>((const float4*)x, (ushort4*)d_out,
                                        (MM * DD) / 4);
    // 2) W -> reordered bf16
    convert_W<<<NN, 128, 0, stream>>>(W, Wr);
    // 3) fused MFMA GEMM + gates: reads bf16 x from d_out, writes u (fp32) in place
    gemm_gate_mfma<<<MM / 64, 512, 0, stream>>>(Wr, F_arr, d_out);
    // 4-6) chunked scan
    scan_pass1<<<BB * CC, HH, 0, stream>>>(F_arr, (const float*)d_out, P_arr, U_arr);
    scan_pass2<<<BB, HH, 0, stream>>>(h_prev, P_arr, U_arr, Hin);
    scan_pass3<<<BB * CC, HH, 0, stream>>>(F_arr, Hin, (float*)d_out);
}

// Round 3
// 346.773 us; speedup vs baseline: 3.4834x; 1.1185x over previous
//
#include <hip/hip_runtime.h>
#include <math.h>

// Problem constants
#define BB 8
#define SS 8192
#define DD 512
#define HH 256
#define MM (BB * SS)        // 65536 rows
#define NN 768              // 3H columns
// Scan chunking
#define CC 64
#define LL 128

typedef unsigned short u16;
typedef __attribute__((ext_vector_type(8))) short short8;   // 8 bf16 = MFMA A/B frag
typedef __attribute__((ext_vector_type(4))) float f32x4;    // MFMA C/D frag

#define AS1(p) ((const __attribute__((address_space(1))) void*)(p))
#define AS3(p) ((__attribute__((address_space(3))) void*)(p))

__device__ __forceinline__ u16 f2bf_rtne(float f) {
    union { float f; unsigned u; } v; v.f = f;
    unsigned r = v.u + 0x7fffu + ((v.u >> 16) & 1u);
    return (u16)(r >> 16);
}
// pack two floats -> two bf16 (round-to-nearest, no tie-even): low16 = a, high16 = b
__device__ __forceinline__ unsigned pack2_rtn(float a, float b) {
    union { float f; unsigned u; } x, y; x.f = a; y.f = b;
    return ((x.u + 0x8000u) >> 16) | ((y.u + 0x8000u) & 0xffff0000u);
}

__device__ __forceinline__ float sp_fast(float z) {    // softplus
    return (z > 15.0f) ? z : __logf(1.0f + __expf(z));
}

// ---- W fp32 [3H,D] -> Wr bf16, permuted into exact DMA staging order:
//   flat chunk id = (kc*2 + half)*1536 + cl*4 + qq   (each chunk = 8 bf16 = 16 B)
//   col c = half*384 + cl;  hg = c/48; g = (c%48)/16; hl = c%16
//   W row = g*256 + hg*16 + hl;  k = kc*32 + qq*8
__global__ __launch_bounds__(256) void convert_W(const float* __restrict__ W,
                                                 u16* __restrict__ Wr) {
    const int chunk = blockIdx.x * 256 + threadIdx.x;    // 0..49151
    const int kh = chunk / 1536;
    const int rem = chunk % 1536;
    const int cl = rem >> 2, qq = rem & 3;
    const int kc = kh >> 1, half = kh & 1;
    const int c = half * 384 + cl;
    const int hg = c / 48, r48 = c % 48;
    const int g = r48 >> 4, hl = r48 & 15;
    const int wrow = g * HH + hg * 16 + hl;
    const int k0 = kc * 32 + qq * 8;
    const float4 v0 = *(const float4*)&W[(size_t)wrow * DD + k0];
    const float4 v1 = *(const float4*)&W[(size_t)wrow * DD + k0 + 4];
    u16 o[8];
    o[0]=f2bf_rtne(v0.x); o[1]=f2bf_rtne(v0.y); o[2]=f2bf_rtne(v0.z); o[3]=f2bf_rtne(v0.w);
    o[4]=f2bf_rtne(v1.x); o[5]=f2bf_rtne(v1.y); o[6]=f2bf_rtne(v1.z); o[7]=f2bf_rtne(v1.w);
    *(uint4*)&Wr[(size_t)chunk * 8] = *(const uint4*)o;
}

// ---- Fused MFMA GEMM + gates, v3.
// Grid: 1024 blocks (BM=64 rows each), 512 threads (8 waves).
// B streamed from L2 in 24 KB halves (double-buffered DMA); A staged fp32->bf16
// through registers once per k-chunk; no convert_x pass; no d_out aliasing.
__global__ __launch_bounds__(512) void gemm_gate_mfma(
    const float* __restrict__ x,      // [M,512] fp32
    const u16* __restrict__ Wr,       // permuted bf16
    float* __restrict__ F_arr,        // [M,H]
    float* __restrict__ u_out)        // d_out: [M,H]
{
    __shared__ __align__(16) u16 Bs[2][12288];        // 2 x 24 KB (384 cols x 32 k)
    __shared__ __align__(16) u16 As[2][64 * 40];      // 2 x 5 KB, row stride 40 shorts (80 B)

    const int tid = threadIdx.x;
    const int m0 = blockIdx.x * 64;
    const int w = tid >> 6;          // wave 0..7
    const int lane = tid & 63;
    const int l16 = lane & 15;
    const int quad = lane >> 4;      // 0..3

    // A staging slot for this thread
    const int arow = tid >> 3;       // 0..63
    const int aqi = tid & 7;         // 0..7 (4 floats each)

    f32x4 acc[4][6];
    #pragma unroll
    for (int a = 0; a < 4; ++a)
        #pragma unroll
        for (int b = 0; b < 6; ++b)
            #pragma unroll
            for (int e = 0; e < 4; ++e) acc[a][b][e] = 0.0f;

    // ---- prologue ----
    // B(kc=0, half0) -> Bs[0]
    #pragma unroll
    for (int i = 0; i < 3; ++i) {
        const int idx = i * 512 + tid;
        __builtin_amdgcn_global_load_lds(AS1(Wr + (size_t)idx * 8),
                                         AS3(&Bs[0][idx * 8]), 16, 0, 0);
    }
    // A(0) via regs -> As[0]
    {
        const float4 v = *(const float4*)&x[(size_t)(m0 + arow) * DD + aqi * 4];
        *(uint2*)&As[0][arow * 40 + aqi * 4] =
            make_uint2(pack2_rtn(v.x, v.y), pack2_rtn(v.z, v.w));
    }
    // prefetch A(1) into regs
    float4 a_reg = *(const float4*)&x[(size_t)(m0 + arow) * DD + 32 + aqi * 4];
    __syncthreads();

    // ---- K loop: 16 kc x 2 halves ----
    for (int kc = 0; kc < 16; ++kc) {
        // issue B(kc, half1) -> Bs[1]  (in flight during half0 compute)
        {
            const size_t base = ((size_t)(kc * 2 + 1)) * 12288;
            #pragma unroll
            for (int i = 0; i < 3; ++i) {
                const int idx = i * 512 + tid;
                __builtin_amdgcn_global_load_lds(AS1(Wr + base + (size_t)idx * 8),
                                                 AS3(&Bs[1][idx * 8]), 16, 0, 0);
            }
        }
        // A fragments for this kc (bf16 in LDS)
        short8 afr[4];
        #pragma unroll
        for (int mf = 0; mf < 4; ++mf)
            afr[mf] = *(const short8*)&As[kc & 1][(mf * 16 + l16) * 40 + quad * 8];

        // ---- half 0 ----
        {
            short8 bfr[3];
            #pragma unroll
            for (int jn = 0; jn < 3; ++jn)
                bfr[jn] = *(const short8*)&Bs[0][((w * 3 + jn) * 16 + l16) * 32 + quad * 8];
            #pragma unroll
            for (int mf = 0; mf < 4; ++mf)
                #pragma unroll
                for (int jn = 0; jn < 3; ++jn)
                    acc[mf][jn] = __builtin_amdgcn_mfma_f32_16x16x32_bf16(
                        afr[mf], bfr[jn], acc[mf][jn], 0, 0, 0);
        }
        // stage A(kc+1) from regs; prefetch A(kc+2)
        *(uint2*)&As[(kc + 1) & 1][arow * 40 + aqi * 4] =
            make_uint2(pack2_rtn(a_reg.x, a_reg.y), pack2_rtn(a_reg.z, a_reg.w));
        {
            const int knext = (kc + 2 < 16) ? (kc + 2) : 15;
            a_reg = *(const float4*)&x[(size_t)(m0 + arow) * DD + knext * 32 + aqi * 4];
        }
        __syncthreads();   // drains B(kc,h1) + A writes; Bs[0] consumed

        // issue B(kc+1, half0) -> Bs[0]
        if (kc < 15) {
            const size_t base = ((size_t)((kc + 1) * 2)) * 12288;
            #pragma unroll
            for (int i = 0; i < 3; ++i) {
                const int idx = i * 512 + tid;
                __builtin_amdgcn_global_load_lds(AS1(Wr + base + (size_t)idx * 8),
                                                 AS3(&Bs[0][idx * 8]), 16, 0, 0);
            }
        }
        // ---- half 1 ----
        {
            short8 bfr[3];
            #pragma unroll
            for (int jn = 0; jn < 3; ++jn)
                bfr[jn] = *(const short8*)&Bs[1][((w * 3 + jn) * 16 + l16) * 32 + quad * 8];
            #pragma unroll
            for (int mf = 0; mf < 4; ++mf)
                #pragma unroll
                for (int jn = 0; jn < 3; ++jn)
                    acc[mf][3 + jn] = __builtin_amdgcn_mfma_f32_16x16x32_bf16(
                        afr[mf], bfr[jn], acc[mf][3 + jn], 0, 0, 0);
        }
        __syncthreads();   // drains B(kc+1,h0); Bs[1] consumed
    }

    // ---- epilogue: gates. head = (half*8 + w)*16 + l16, gate g = jn ----
    #pragma unroll
    for (int half = 0; half < 2; ++half) {
        const int head = (half * 8 + w) * 16 + l16;
        #pragma unroll
        for (int mf = 0; mf < 4; ++mf) {
            #pragma unroll
            for (int r = 0; r < 4; ++r) {
                const int m = m0 + mf * 16 + quad * 4 + r;
                const float fr = acc[mf][half * 3 + 0][r];
                const float ir = acc[mf][half * 3 + 1][r];
                const float hr = acc[mf][half * 3 + 2][r];
                const float diff = sp_fast(-fr) - sp_fast(-ir);
                const float F = __builtin_amdgcn_rcpf(1.0f + __expf(diff));
                const float I = 1.0f - F;
                const float G = (hr >= 0.0f) ? (hr + 0.5f)
                                             : __builtin_amdgcn_rcpf(1.0f + __expf(-hr));
                const size_t o = (size_t)m * HH + head;
                F_arr[o] = F;
                u_out[o] = I * G;
            }
        }
    }
}

// ---- Scan passes (proven) ----
__global__ __launch_bounds__(256) void scan_pass1(
    const float* __restrict__ F_arr, const float* __restrict__ u_arr,
    float* __restrict__ P_arr, float* __restrict__ U_arr) {
    const int bc = blockIdx.x;
    const int b = bc / CC;
    const int c = bc % CC;
    const int h = threadIdx.x;
    size_t base = ((size_t)(b * SS + c * LL)) * HH + h;
    float P = 1.0f, U = 0.0f;
    #pragma unroll 4
    for (int t = 0; t < LL; ++t) {
        const float F = F_arr[base];
        const float u = u_arr[base];
        U = F * U + u;
        P = P * F;
        base += HH;
    }
    const size_t o = ((size_t)c * BB + b) * HH + h;
    P_arr[o] = P;
    U_arr[o] = U;
}

__global__ __launch_bounds__(256) void scan_pass2(
    const float* __restrict__ h_prev, const float* __restrict__ P_arr,
    const float* __restrict__ U_arr, float* __restrict__ Hin) {
    const int b = blockIdx.x;
    const int h = threadIdx.x;
    const float z = h_prev[b * HH + h];
    float carry = (z >= 0.0f) ? (z + 0.5f) : __builtin_amdgcn_rcpf(1.0f + __expf(-z));
    for (int c = 0; c < CC; ++c) {
        const size_t o = ((size_t)c * BB + b) * HH + h;
        Hin[o] = carry;
        carry = P_arr[o] * carry + U_arr[o];
    }
}

__global__ __launch_bounds__(256) void scan_pass3(
    const float* __restrict__ F_arr, const float* __restrict__ Hin,
    float* __restrict__ out) {
    const int bc = blockIdx.x;
    const int b = bc / CC;
    const int c = bc % CC;
    const int h = threadIdx.x;
    float hv = Hin[((size_t)c * BB + b) * HH + h];
    size_t base = ((size_t)(b * SS + c * LL)) * HH + h;
    #pragma unroll 4
    for (int t = 0; t < LL; ++t) {
        const float F = F_arr[base];
        const float u = out[base];
        hv = F * hv + u;
        out[base] = hv;
        base += HH;
    }
}

extern "C" void kernel_launch(void* const* d_in, const int* in_sizes, int n_in,
                              void* d_out, int out_size, void* d_ws, size_t ws_size,
                              hipStream_t stream) {
    const float* x      = (const float*)d_in[0];   // [B,S,D]
    const float* h_prev = (const float*)d_in[1];   // [B,H]
    const float* W      = (const float*)d_in[2];   // [3H,D]

    // Workspace: F_arr [M*H] f32 | P | U | Hin | Wr [768*512] bf16  (~69.4 MB, proven)
    float* F_arr = (float*)d_ws;
    float* P_arr = F_arr + (size_t)MM * HH;
    float* U_arr = P_arr + (size_t)CC * BB * HH;
    float* Hin   = U_arr + (size_t)CC * BB * HH;
    u16*   Wr    = (u16*)(Hin + (size_t)CC * BB * HH);

    convert_W<<<192, 256, 0, stream>>>(W, Wr);
    gemm_gate_mfma<<<MM / 64, 512, 0, stream>>>(x, Wr, F_arr, (float*)d_out);
    scan_pass1<<<BB * CC, HH, 0, stream>>>(F_arr, (const float*)d_out, P_arr, U_arr);
    scan_pass2<<<BB, HH, 0, stream>>>(h_prev, P_arr, U_arr, Hin);
    scan_pass3<<<BB * CC, HH, 0, stream>>>(F_arr, Hin, (float*)d_out);
}